// Round 12
// baseline (1062.329 us; speedup 1.0000x reference)
//
#include <hip/hip_runtime.h>
#include <hip/hip_bf16.h>

typedef __attribute__((ext_vector_type(8))) short short8;
typedef __attribute__((ext_vector_type(4))) float f32x4;
typedef __attribute__((ext_vector_type(2))) unsigned int u32x2;
typedef __attribute__((ext_vector_type(4))) unsigned int u32x4;

#define N_NODES  200000
#define N_EDGES  800000
#define N_GRAPHS 8000

__device__ __forceinline__ unsigned short f2bf(float f) {
  unsigned int u = __float_as_uint(f);
  unsigned int r = (u + 0x7fffu + ((u >> 16) & 1u)) >> 16;
  return (unsigned short)r;
}
__device__ __forceinline__ float bf2f(unsigned short s) {
  return __uint_as_float(((unsigned int)s) << 16);
}
// pack 2 fp32 -> u32 of 2 bf16 via v_cvt_pk_bf16_f32
__device__ __forceinline__ unsigned cvtpk(float a, float b) {
  union { __hip_bfloat162 h; unsigned u; } cv;
  cv.h = __float22bfloat162_rn(make_float2(a, b));
  return cv.u;
}

// 4x4 bf16 transpose across 4 lanes (lanes differing in bits 0,1).
__device__ __forceinline__ void xpose4(unsigned W0, unsigned W1, int bsub,
                                       unsigned selT, unsigned& T0, unsigned& T1) {
  unsigned t0 = (unsigned)__shfl_xor((int)W0, 2);
  unsigned t1 = (unsigned)__shfl_xor((int)W1, 2);
  unsigned A0 = (bsub & 2) ? t1 : W0;
  unsigned A1 = (bsub & 2) ? W1 : t0;
  unsigned t2 = (unsigned)__shfl_xor((int)A0, 1);
  unsigned t3 = (unsigned)__shfl_xor((int)A1, 1);
  T0 = __builtin_amdgcn_perm(A0, t2, selT);
  T1 = __builtin_amdgcn_perm(A1, t3, selT);
}

// ---------------------------------------------------------------------------
// Weight convert to FRAGMENT-ORDERED bf16 (r11 win: +35% on edge MLP):
//   wf[ (((c>>4)*KT + kt)*64 + lane)*8 + j ] = w[ kt*32 + (lane>>4)*8 + j ][ c ]
// A wave's B-fragment load is one contiguous 1KB block (was a 16-line scatter).
// ---------------------------------------------------------------------------
__global__ void wtrans_frag(const float* __restrict__ w, unsigned short* __restrict__ wf,
                            int K, int Nc) {
  int id = blockIdx.x * 256 + threadIdx.x;
  if (id >= K * Nc) return;
  int j    = id & 7;
  int lane = (id >> 3) & 63;
  int rest = id >> 9;            // cb*KT + kt
  int KT   = K >> 5;
  int kt   = rest % KT;
  int cb   = rest / KT;
  int c = cb * 16 + (lane & 15);
  int k = kt * 32 + (lane >> 4) * 8 + j;
  wf[id] = f2bf(w[k * Nc + c]);
}

// fp32 -> bf16 bulk convert (8 elems/thread)
__global__ __launch_bounds__(256) void f2bf_bulk(const float* __restrict__ x,
                                                 unsigned short* __restrict__ xb,
                                                 int n8) {
  int id = blockIdx.x * 256 + threadIdx.x;
  if (id >= n8) return;
  float4 a = ((const float4*)x)[id * 2];
  float4 b = ((const float4*)x)[id * 2 + 1];
  u32x4 pk = {cvtpk(a.x, a.y), cvtpk(a.z, a.w), cvtpk(b.x, b.y), cvtpk(b.z, b.w)};
  ((u32x4*)xb)[id] = pk;
}

// ---------------------------------------------------------------------------
// Staging: slab s of the 64-row input tile -> bf16 into ab (swizzled).
// Pure 16B copy (bf16 X, stride K1). r12: convs also use this path -- the
// GINE self-term add moved into gather_agg, so agg is MLP-ready.
// ---------------------------------------------------------------------------
template <int K1, int SLAB, int NKK>
__device__ __forceinline__ void stage_slab(
    int s, char* ab, int row0, int srow, int skk,
    const unsigned short* __restrict__ Xb) {
#pragma unroll
  for (int c2 = 0; c2 < NKK; ++c2) {
    const int kloc = skk + 32 * c2;
    const int gk = s * SLAB + kloc;
    int off = srow * (2 * SLAB) + kloc * 2;
    off ^= (srow & 7) << 4;
    u32x4 d = *(const u32x4*)(Xb + (size_t)(row0 + srow) * K1 + gk);
    *(u32x4*)(ab + off) = d;
  }
}

// ---------------------------------------------------------------------------
// Fused 2-layer MLP: out = [relu?](relu(X @ W1 + b1) @ W2 + b2), N=256 cols.
// 64 rows x 256 cols per block, 4 waves (r6 structure -- best measured).
// Weights in FRAGMENT order (r11): wave's bq load = one coalesced 1KB block.
// LDS = 32KB union (a-slabs alias hidden; K=256 double-buffers two 16KB slabs).
// NOTE: no min-waves launch_bounds clause -- (256,5) forced spills (r5).
// r7: A-frags direct from global are uncoalesced -- keep LDS staging.
// r9: smaller tile regressed. r10: gather-in-staging regressed.
// ---------------------------------------------------------------------------
template <int K1>
__global__ __launch_bounds__(256) void fused_mlp2(
    const unsigned short* __restrict__ Xb,
    const unsigned short* __restrict__ w1f, const float* __restrict__ b1,
    const unsigned short* __restrict__ w2f, const float* __restrict__ b2,
    unsigned short* __restrict__ out, int relu_out) {
  constexpr int SLAB  = (K1 < 128) ? K1 : 128;
  constexpr int NSLAB = K1 / SLAB;
  constexpr int NKK   = SLAB / 32;
  constexpr int KT1   = K1 / 32;
  __shared__ unsigned short h_lds[64 * 256];   // 32 KB: a-slabs + hidden + out
  char* hbase = (char*)h_lds;

  const int tid  = threadIdx.x;
  const int row0 = blockIdx.x * 64;
  const int lane = tid & 63;
  const int wid  = tid >> 6;
  const int lr   = lane & 15;
  const int kq   = lane >> 4;
  const int col0 = wid * 64;
  const int cb0  = wid * 4;     // 16-col block index of this wave's first tile
  const int bsub = lr & 3;
  const int asub = lr >> 2;
  const unsigned selT = (bsub & 1) ? 0x07060302u : 0x01000504u;

  const int srow = tid >> 2;
  const int skk  = (tid & 3) * 8;

  f32x4 acc[4][4];
#pragma unroll
  for (int m = 0; m < 4; ++m)
#pragma unroll
    for (int n = 0; n < 4; ++n) acc[m][n] = (f32x4){0.f, 0.f, 0.f, 0.f};

  float bias1[4];
#pragma unroll
  for (int n = 0; n < 4; ++n) bias1[n] = b1[col0 + n * 16 + lr];

  // ---------------- phase A: hidden = relu(X @ W1 + b1) ------------------
  stage_slab<K1, SLAB, NKK>(0, hbase, row0, srow, skk, Xb);
  __syncthreads();

#pragma unroll
  for (int s = 0; s < NSLAB; ++s) {
    if (s + 1 < NSLAB)  // double-buffer: stage next slab into the other 16KB
      stage_slab<K1, SLAB, NKK>(s + 1, hbase + 16384, row0, srow, skk, Xb);
    char* ab = hbase + (s & 1) * 16384;
#pragma unroll
    for (int kk = 0; kk < NKK; ++kk) {
      short8 af[4], bq[4];
#pragma unroll
      for (int m = 0; m < 4; ++m) {
        int r = m * 16 + lr;
        int off = r * (2 * SLAB) + kk * 64 + kq * 16;
        off ^= (r & 7) << 4;
        af[m] = *(short8*)(ab + off);
      }
      const int kt = s * NKK + kk;
#pragma unroll
      for (int n = 0; n < 4; ++n)
        bq[n] = *(const short8*)(w1f + ((size_t)(cb0 + n) * KT1 + kt) * 512 + lane * 8);
#pragma unroll
      for (int m = 0; m < 4; ++m)
#pragma unroll
        for (int n = 0; n < 4; ++n)
          acc[m][n] = __builtin_amdgcn_mfma_f32_16x16x32_bf16(af[m], bq[n], acc[m][n], 0, 0, 0);
    }
    __syncthreads();  // a-slab reads done (last iter: before epiA overwrites)
  }

  // epilogue A: bias + relu, 4x4 lane-transpose, 8B writes -> h layout
#pragma unroll
  for (int n = 0; n < 4; ++n) {
    float bn = bias1[n];
#pragma unroll
    for (int m = 0; m < 4; ++m) {
      float v0 = fmaxf(acc[m][n][0] + bn, 0.f);
      float v1 = fmaxf(acc[m][n][1] + bn, 0.f);
      float v2 = fmaxf(acc[m][n][2] + bn, 0.f);
      float v3 = fmaxf(acc[m][n][3] + bn, 0.f);
      unsigned W0 = cvtpk(v0, v1), W1 = cvtpk(v2, v3), T0, T1;
      xpose4(W0, W1, bsub, selT, T0, T1);
      int r = m * 16 + kq * 4 + bsub;
      int cb = col0 + n * 16 + asub * 4;
      int off = r * 512 + cb * 2;
      off ^= (r & 7) << 4;
      *(u32x2*)(hbase + off) = (u32x2){T0, T1};
    }
  }
  __syncthreads();

  // ---------------- phase B: out = hidden @ W2 + b2 ----------------------
#pragma unroll
  for (int m = 0; m < 4; ++m)
#pragma unroll
    for (int n = 0; n < 4; ++n) acc[m][n] = (f32x4){0.f, 0.f, 0.f, 0.f};

  float bias2[4];
#pragma unroll
  for (int n = 0; n < 4; ++n) bias2[n] = b2[col0 + n * 16 + lr];

#pragma unroll
  for (int ks = 0; ks < 8; ++ks) {
    short8 af[4], bq[4];
#pragma unroll
    for (int m = 0; m < 4; ++m) {
      int r = m * 16 + lr;
      int off = r * 512 + ks * 64 + kq * 16;
      off ^= (r & 7) << 4;
      af[m] = *(short8*)(hbase + off);
    }
#pragma unroll
    for (int n = 0; n < 4; ++n)
      bq[n] = *(const short8*)(w2f + ((size_t)(cb0 + n) * 8 + ks) * 512 + lane * 8);
#pragma unroll
    for (int m = 0; m < 4; ++m)
#pragma unroll
      for (int n = 0; n < 4; ++n)
        acc[m][n] = __builtin_amdgcn_mfma_f32_16x16x32_bf16(af[m], bq[n], acc[m][n], 0, 0, 0);
  }
  __syncthreads();  // all waves done READING h_lds before overwrite

  // epilogue B: bias (+relu), transpose, write tile into h_lds
#pragma unroll
  for (int n = 0; n < 4; ++n) {
    float bn = bias2[n];
#pragma unroll
    for (int m = 0; m < 4; ++m) {
      float v0 = acc[m][n][0] + bn;
      float v1 = acc[m][n][1] + bn;
      float v2 = acc[m][n][2] + bn;
      float v3 = acc[m][n][3] + bn;
      if (relu_out) {
        v0 = fmaxf(v0, 0.f); v1 = fmaxf(v1, 0.f);
        v2 = fmaxf(v2, 0.f); v3 = fmaxf(v3, 0.f);
      }
      unsigned W0 = cvtpk(v0, v1), W1 = cvtpk(v2, v3), T0, T1;
      xpose4(W0, W1, bsub, selT, T0, T1);
      int r = m * 16 + kq * 4 + bsub;
      int cb = col0 + n * 16 + asub * 4;
      int off = r * 512 + cb * 2;
      off ^= (r & 7) << 4;
      *(u32x2*)(hbase + off) = (u32x2){T0, T1};
    }
  }
  __syncthreads();

  // coalesced copy h_lds -> out: each half-wave writes one full 512B row
#pragma unroll
  for (int it = 0; it < 8; ++it) {
    int r = (tid >> 5) + it * 8;
    int byte = (tid & 31) * 16;
    int off = (r * 512 + byte) ^ ((r & 7) << 4);
    u32x4 d = *(u32x4*)(hbase + off);
    *(u32x4*)((char*)out + (size_t)(row0 + r) * 512 + byte) = d;
  }
}

// ---------------------------------------------------------------------------
// CSR build: rp = degree hist -> (scan+fill) per-node END offsets.
// ---------------------------------------------------------------------------
__global__ void hist_deg(const int* __restrict__ dst, int* __restrict__ rp) {
  int e = blockIdx.x * 256 + threadIdx.x;
  if (e < N_EDGES) atomicAdd(&rp[dst[e]], 1);
}

__global__ __launch_bounds__(256) void scan_block(int* __restrict__ rp,
                                                  int* __restrict__ bsum) {
  __shared__ int ts[256];
  int b = blockIdx.x, t = threadIdx.x;
  int base = b * 2048 + t * 8;
  int v[8]; int s = 0;
#pragma unroll
  for (int i = 0; i < 8; ++i) {
    int idx = base + i;
    v[i] = (idx < N_NODES) ? rp[idx] : 0;
    s += v[i];
  }
  ts[t] = s;
  __syncthreads();
#pragma unroll
  for (int off = 1; off < 256; off <<= 1) {
    int add = (t >= off) ? ts[t - off] : 0;
    __syncthreads();
    ts[t] += add;
    __syncthreads();
  }
  int excl = ts[t] - s;
  if (t == 255) bsum[b] = ts[255];
  int run = excl;
#pragma unroll
  for (int i = 0; i < 8; ++i) {
    int idx = base + i;
    if (idx < N_NODES) rp[idx] = run;
    run += v[i];
  }
}

__global__ __launch_bounds__(256) void scan_bsum(int* __restrict__ bsum, int nb) {
  __shared__ int ts[256];
  int t = threadIdx.x;
  int v = (t < nb) ? bsum[t] : 0;
  ts[t] = v;
  __syncthreads();
#pragma unroll
  for (int off = 1; off < 256; off <<= 1) {
    int add = (t >= off) ? ts[t - off] : 0;
    __syncthreads();
    ts[t] += add;
    __syncthreads();
  }
  if (t < nb) bsum[t] = ts[t] - v;  // exclusive
}

__global__ void scan_add(int* __restrict__ rp, const int* __restrict__ bsum) {
  int i = blockIdx.x * 256 + threadIdx.x;
  if (i < N_NODES) rp[i] += bsum[i >> 11];
}

__global__ void csr_fill(const int* __restrict__ src, const int* __restrict__ dst,
                         int* __restrict__ rp, int2* __restrict__ csr) {
  int e = blockIdx.x * 256 + threadIdx.x;
  if (e >= N_EDGES) return;
  int d = dst[e];
  int p = atomicAdd(&rp[d], 1);
  csr[p] = make_int2(src[e], e);
}

// ---------------------------------------------------------------------------
// Gather-aggregate (r12): agg[v] = x_v + sum_{e: dst(e)=v} relu(x_src + ea_e)
// (self-term absorbed here so the conv MLP staging is a pure copy).
// One wave per node, 4 cols/lane, 4-edge unroll for more loads in flight.
// ---------------------------------------------------------------------------
__global__ __launch_bounds__(256) void gather_agg(
    const unsigned short* __restrict__ ea, const unsigned short* __restrict__ xb,
    const int* __restrict__ rp, const int2* __restrict__ csr,
    unsigned short* __restrict__ agg) {
  int v = blockIdx.x * 4 + (threadIdx.x >> 6);
  if (v >= N_NODES) return;
  int lane = threadIdx.x & 63;
  int c = lane * 4;
  int beg = (v == 0) ? 0 : rp[v - 1];
  int end = rp[v];
  ushort4 sv = *(const ushort4*)(xb + (size_t)v * 256 + c);
  float a0 = bf2f(sv.x), a1 = bf2f(sv.y), a2 = bf2f(sv.z), a3 = bf2f(sv.w);
  int i = beg;
  for (; i + 4 <= end; i += 4) {
    int2 s0 = csr[i], s1 = csr[i + 1], s2 = csr[i + 2], s3 = csr[i + 3];
    ushort4 e0 = *(const ushort4*)(ea + (size_t)s0.y * 256 + c);
    ushort4 e1 = *(const ushort4*)(ea + (size_t)s1.y * 256 + c);
    ushort4 e2 = *(const ushort4*)(ea + (size_t)s2.y * 256 + c);
    ushort4 e3 = *(const ushort4*)(ea + (size_t)s3.y * 256 + c);
    ushort4 h0 = *(const ushort4*)(xb + (size_t)s0.x * 256 + c);
    ushort4 h1 = *(const ushort4*)(xb + (size_t)s1.x * 256 + c);
    ushort4 h2 = *(const ushort4*)(xb + (size_t)s2.x * 256 + c);
    ushort4 h3 = *(const ushort4*)(xb + (size_t)s3.x * 256 + c);
    a0 += fmaxf(bf2f(h0.x) + bf2f(e0.x), 0.f) + fmaxf(bf2f(h1.x) + bf2f(e1.x), 0.f)
        + fmaxf(bf2f(h2.x) + bf2f(e2.x), 0.f) + fmaxf(bf2f(h3.x) + bf2f(e3.x), 0.f);
    a1 += fmaxf(bf2f(h0.y) + bf2f(e0.y), 0.f) + fmaxf(bf2f(h1.y) + bf2f(e1.y), 0.f)
        + fmaxf(bf2f(h2.y) + bf2f(e2.y), 0.f) + fmaxf(bf2f(h3.y) + bf2f(e3.y), 0.f);
    a2 += fmaxf(bf2f(h0.z) + bf2f(e0.z), 0.f) + fmaxf(bf2f(h1.z) + bf2f(e1.z), 0.f)
        + fmaxf(bf2f(h2.z) + bf2f(e2.z), 0.f) + fmaxf(bf2f(h3.z) + bf2f(e3.z), 0.f);
    a3 += fmaxf(bf2f(h0.w) + bf2f(e0.w), 0.f) + fmaxf(bf2f(h1.w) + bf2f(e1.w), 0.f)
        + fmaxf(bf2f(h2.w) + bf2f(e2.w), 0.f) + fmaxf(bf2f(h3.w) + bf2f(e3.w), 0.f);
  }
  for (; i < end; ++i) {
    int2 se = csr[i];
    ushort4 ev = *(const ushort4*)(ea + (size_t)se.y * 256 + c);
    ushort4 hv = *(const ushort4*)(xb + (size_t)se.x * 256 + c);
    a0 += fmaxf(bf2f(hv.x) + bf2f(ev.x), 0.f);
    a1 += fmaxf(bf2f(hv.y) + bf2f(ev.y), 0.f);
    a2 += fmaxf(bf2f(hv.z) + bf2f(ev.z), 0.f);
    a3 += fmaxf(bf2f(hv.w) + bf2f(ev.w), 0.f);
  }
  u32x2 pk = {cvtpk(a0, a1), cvtpk(a2, a3)};
  *(u32x2*)(agg + (size_t)v * 256 + c) = pk;
}

// ---------------------------------------------------------------------------
// Pool: mean of h2 rows per graph; 4 rows in flight, ushort4 loads.
// ---------------------------------------------------------------------------
__global__ __launch_bounds__(256) void pool_mean(const unsigned short* __restrict__ h2,
                                                 const int* __restrict__ batch,
                                                 float* __restrict__ pooled) {
  int g = blockIdx.x;
  int tid = threadIdx.x;
  int lane = tid & 63;   // col group (4 cols)
  int sub = tid >> 6;    // row offset 0..3
  int lo = 0, hi = N_NODES;
  while (lo < hi) { int mid = (lo + hi) >> 1; if (batch[mid] < g) lo = mid + 1; else hi = mid; }
  int start = lo;
  hi = N_NODES;
  while (lo < hi) { int mid = (lo + hi) >> 1; if (batch[mid] < g + 1) lo = mid + 1; else hi = mid; }
  int end = lo;
  float s0 = 0.f, s1 = 0.f, s2 = 0.f, s3 = 0.f;
  for (int r = start + sub; r < end; r += 4) {
    ushort4 hv = *(const ushort4*)(h2 + (size_t)r * 256 + lane * 4);
    s0 += bf2f(hv.x); s1 += bf2f(hv.y); s2 += bf2f(hv.z); s3 += bf2f(hv.w);
  }
  __shared__ float4 red[4][64];
  red[sub][lane] = make_float4(s0, s1, s2, s3);
  __syncthreads();
  if (sub == 0) {
    float4 a = red[0][lane], b = red[1][lane], cc = red[2][lane], d = red[3][lane];
    float inv = 1.0f / fmaxf((float)(end - start), 1.0f);
    float4 t = make_float4((a.x + b.x + cc.x + d.x) * inv,
                           (a.y + b.y + cc.y + d.y) * inv,
                           (a.z + b.z + cc.z + d.z) * inv,
                           (a.w + b.w + cc.w + d.w) * inv);
    *(float4*)(pooled + (size_t)g * 256 + lane * 4) = t;
  }
}

// ---------------------------------------------------------------------------
// Heads: g1=relu(p@l1+b) [128], g2=relu(g1@l2+b) [64], 3 dot-products
// ---------------------------------------------------------------------------
__global__ __launch_bounds__(128) void head_mlp(
    const float* __restrict__ pooled, const float* __restrict__ l1w,
    const float* __restrict__ l1b, const float* __restrict__ l2w,
    const float* __restrict__ l2b, const float* __restrict__ hSw,
    const float* __restrict__ hSb, const float* __restrict__ hPw,
    const float* __restrict__ hPb, const float* __restrict__ hNw,
    const float* __restrict__ hNb, float* __restrict__ out) {
  int g = blockIdx.x, tid = threadIdx.x;
  __shared__ float p[256];
  __shared__ float g1[128];
  __shared__ float g2[64];
  p[tid] = pooled[(size_t)g * 256 + tid];
  p[tid + 128] = pooled[(size_t)g * 256 + tid + 128];
  __syncthreads();
  float a = l1b[tid];
#pragma unroll 8
  for (int k = 0; k < 256; ++k) a += p[k] * l1w[k * 128 + tid];
  g1[tid] = fmaxf(a, 0.f);
  __syncthreads();
  if (tid < 64) {
    float b = l2b[tid];
#pragma unroll 8
    for (int k = 0; k < 128; ++k) b += g1[k] * l2w[k * 64 + tid];
    g2[tid] = fmaxf(b, 0.f);
  }
  __syncthreads();
  if (tid < 64) {
    float v = g2[tid];
    float s = v * hSw[tid], pq = v * hPw[tid], nq = v * hNw[tid];
#pragma unroll
    for (int off = 32; off > 0; off >>= 1) {
      s  += __shfl_down(s, off);
      pq += __shfl_down(pq, off);
      nq += __shfl_down(nq, off);
    }
    if (tid == 0) {
      out[g]                = s  + hSb[0];
      out[N_GRAPHS + g]     = pq + hPb[0];
      out[2 * N_GRAPHS + g] = nq + hNb[0];
    }
  }
}

// ---------------------------------------------------------------------------
extern "C" void kernel_launch(void* const* d_in, const int* in_sizes, int n_in,
                              void* d_out, int out_size, void* d_ws, size_t ws_size,
                              hipStream_t stream) {
  const float* x         = (const float*)d_in[0];
  const float* edge_attr = (const float*)d_in[1];
  const int*   ei        = (const int*)d_in[2];
  const int*   batch     = (const int*)d_in[3];
  const float* em_w1 = (const float*)d_in[4];  const float* em_b1 = (const float*)d_in[5];
  const float* em_w2 = (const float*)d_in[6];  const float* em_b2 = (const float*)d_in[7];
  const float* c1_w1 = (const float*)d_in[8];  const float* c1_b1 = (const float*)d_in[9];
  const float* c1_w2 = (const float*)d_in[10]; const float* c1_b2 = (const float*)d_in[11];
  const float* c2_w1 = (const float*)d_in[12]; const float* c2_b1 = (const float*)d_in[13];
  const float* c2_w2 = (const float*)d_in[14]; const float* c2_b2 = (const float*)d_in[15];
  const float* l1_w = (const float*)d_in[16];  const float* l1_b = (const float*)d_in[17];
  const float* l2_w = (const float*)d_in[18];  const float* l2_b = (const float*)d_in[19];
  const float* hS_w = (const float*)d_in[20];  const float* hS_b = (const float*)d_in[21];
  const float* hP_w = (const float*)d_in[22];  const float* hP_b = (const float*)d_in[23];
  const float* hN_w = (const float*)d_in[24];  const float* hN_b = (const float*)d_in[25];

  char* ws = (char*)d_ws;
  // layout (bytes):
  //   ea   @ 0           : E*256*2 = 409,600,000  (bf16, edge order; h2 later)
  //   agg  @ 409,600,000 : N*256*2 = 102,400,000  (bf16, MLP-ready: + self)
  //   xb   @ 512,000,000 : N*256*2 = 102,400,000  (bf16 copy of x)
  //   h1   @ 614,400,000 : N*256*2 = 102,400,000  <- eab (E*64*2) aliases
  //   pool @ 716,800,000 : G*256*4 =   8,192,000  <- csr/rp/bsum alias
  //   wts  @ 724,992,000 : ~688,128 (fragment-ordered)
  unsigned short* ea     = (unsigned short*)ws;
  unsigned short* agg    = (unsigned short*)(ws + 409600000);
  unsigned short* xb     = (unsigned short*)(ws + 512000000);
  unsigned short* h1     = (unsigned short*)(ws + 614400000);
  unsigned short* eab    = h1;  // alias: eab dead before conv1 writes h1
  unsigned short* h2     = ea;  // alias: ea dead after 2nd gather
  float*          pooled = (float*)(ws + 716800000);
  int2*           csr    = (int2*)(ws + 716800000);            // 6,400,000 B
  int*            rp     = (int*)(ws + 723200000);             //   800,000 B
  int*            bsum   = (int*)(ws + 724000000);             //     1,024 B
  unsigned short* wt     = (unsigned short*)(ws + 724992000);
  unsigned short* em_w1f = wt;                 // 256 x 64
  unsigned short* em_w2f = em_w1f + 16384;     // 256 x 256
  unsigned short* c1_w1f = em_w2f + 65536;
  unsigned short* c1_w2f = c1_w1f + 65536;
  unsigned short* c2_w1f = c1_w2f + 65536;
  unsigned short* c2_w2f = c2_w1f + 65536;

  const int* srcI = ei;
  const int* dstI = ei + N_EDGES;

  wtrans_frag<<<(16384 + 255) / 256, 256, 0, stream>>>(em_w1, em_w1f, 64, 256);
  wtrans_frag<<<(65536 + 255) / 256, 256, 0, stream>>>(em_w2, em_w2f, 256, 256);
  wtrans_frag<<<(65536 + 255) / 256, 256, 0, stream>>>(c1_w1, c1_w1f, 256, 256);
  wtrans_frag<<<(65536 + 255) / 256, 256, 0, stream>>>(c1_w2, c1_w2f, 256, 256);
  wtrans_frag<<<(65536 + 255) / 256, 256, 0, stream>>>(c2_w1, c2_w1f, 256, 256);
  wtrans_frag<<<(65536 + 255) / 256, 256, 0, stream>>>(c2_w2, c2_w2f, 256, 256);

  // bf16 tables: x (node features) and edge_attr
  f2bf_bulk<<<(N_NODES * 256 / 8 + 255) / 256, 256, 0, stream>>>(x, xb, N_NODES * 256 / 8);
  f2bf_bulk<<<(N_EDGES * 64 / 8 + 255) / 256, 256, 0, stream>>>(edge_attr, eab, N_EDGES * 64 / 8);

  // CSR build (by dst)
  hipMemsetAsync(rp, 0, (size_t)N_NODES * 4, stream);
  hist_deg<<<(N_EDGES + 255) / 256, 256, 0, stream>>>(dstI, rp);
  scan_block<<<(N_NODES + 2047) / 2048, 256, 0, stream>>>(rp, bsum);
  scan_bsum<<<1, 256, 0, stream>>>(bsum, (N_NODES + 2047) / 2048);
  scan_add<<<(N_NODES + 255) / 256, 256, 0, stream>>>(rp, bsum);
  csr_fill<<<N_EDGES / 256, 256, 0, stream>>>(srcI, dstI, rp, csr);

  // ea = edge MLP from bf16 edge_attr (no output relu)
  fused_mlp2<64><<<N_EDGES / 64, 256, 0, stream>>>(
      eab, em_w1f, em_b1, em_w2f, em_b2, ea, 0);

  // conv1: gather (with self-term) -> pure-copy-staged MLP
  gather_agg<<<(N_NODES + 3) / 4, 256, 0, stream>>>(ea, xb, rp, csr, agg);
  fused_mlp2<256><<<N_NODES / 64, 256, 0, stream>>>(
      agg, c1_w1f, c1_b1, c1_w2f, c1_b2, h1, 1);

  // conv2
  gather_agg<<<(N_NODES + 3) / 4, 256, 0, stream>>>(ea, h1, rp, csr, agg);
  fused_mlp2<256><<<N_NODES / 64, 256, 0, stream>>>(
      agg, c2_w1f, c2_b1, c2_w2f, c2_b2, h2, 1);

  // pool + heads
  pool_mean<<<N_GRAPHS, 256, 0, stream>>>(h2, batch, pooled);
  head_mlp<<<N_GRAPHS, 128, 0, stream>>>(pooled, l1_w, l1_b, l2_w, l2_b,
                                         hS_w, hS_b, hP_w, hP_b, hN_w, hN_b,
                                         (float*)d_out);
}

// Round 13
// 1012.729 us; speedup vs baseline: 1.0490x; 1.0490x over previous
//
#include <hip/hip_runtime.h>
#include <hip/hip_bf16.h>

typedef __attribute__((ext_vector_type(8))) short short8;
typedef __attribute__((ext_vector_type(4))) float f32x4;
typedef __attribute__((ext_vector_type(2))) unsigned int u32x2;
typedef __attribute__((ext_vector_type(4))) unsigned int u32x4;

#define N_NODES  200000
#define N_EDGES  800000
#define N_GRAPHS 8000

__device__ __forceinline__ unsigned short f2bf(float f) {
  unsigned int u = __float_as_uint(f);
  unsigned int r = (u + 0x7fffu + ((u >> 16) & 1u)) >> 16;
  return (unsigned short)r;
}
__device__ __forceinline__ float bf2f(unsigned short s) {
  return __uint_as_float(((unsigned int)s) << 16);
}
// pack 2 fp32 -> u32 of 2 bf16 via v_cvt_pk_bf16_f32
__device__ __forceinline__ unsigned cvtpk(float a, float b) {
  union { __hip_bfloat162 h; unsigned u; } cv;
  cv.h = __float22bfloat162_rn(make_float2(a, b));
  return cv.u;
}

// 4x4 bf16 transpose across 4 lanes (lanes differing in bits 0,1).
__device__ __forceinline__ void xpose4(unsigned W0, unsigned W1, int bsub,
                                       unsigned selT, unsigned& T0, unsigned& T1) {
  unsigned t0 = (unsigned)__shfl_xor((int)W0, 2);
  unsigned t1 = (unsigned)__shfl_xor((int)W1, 2);
  unsigned A0 = (bsub & 2) ? t1 : W0;
  unsigned A1 = (bsub & 2) ? W1 : t0;
  unsigned t2 = (unsigned)__shfl_xor((int)A0, 1);
  unsigned t3 = (unsigned)__shfl_xor((int)A1, 1);
  T0 = __builtin_amdgcn_perm(A0, t2, selT);
  T1 = __builtin_amdgcn_perm(A1, t3, selT);
}

// ---------------------------------------------------------------------------
// Weight convert to FRAGMENT-ORDERED bf16 (r11 win: +35% on edge MLP):
//   wf[ (((c>>4)*KT + kt)*64 + lane)*8 + j ] = w[ kt*32 + (lane>>4)*8 + j ][ c ]
// A wave's B-fragment load is one contiguous 1KB block (was a 16-line scatter).
// ---------------------------------------------------------------------------
__global__ void wtrans_frag(const float* __restrict__ w, unsigned short* __restrict__ wf,
                            int K, int Nc) {
  int id = blockIdx.x * 256 + threadIdx.x;
  if (id >= K * Nc) return;
  int j    = id & 7;
  int lane = (id >> 3) & 63;
  int rest = id >> 9;            // cb*KT + kt
  int KT   = K >> 5;
  int kt   = rest % KT;
  int cb   = rest / KT;
  int c = cb * 16 + (lane & 15);
  int k = kt * 32 + (lane >> 4) * 8 + j;
  wf[id] = f2bf(w[k * Nc + c]);
}

// fp32 -> bf16 bulk convert (8 elems/thread)
__global__ __launch_bounds__(256) void f2bf_bulk(const float* __restrict__ x,
                                                 unsigned short* __restrict__ xb,
                                                 int n8) {
  int id = blockIdx.x * 256 + threadIdx.x;
  if (id >= n8) return;
  float4 a = ((const float4*)x)[id * 2];
  float4 b = ((const float4*)x)[id * 2 + 1];
  u32x4 pk = {cvtpk(a.x, a.y), cvtpk(a.z, a.w), cvtpk(b.x, b.y), cvtpk(b.z, b.w)};
  ((u32x4*)xb)[id] = pk;
}

// ---------------------------------------------------------------------------
// Staging: slab s of the 64-row input tile -> bf16 into ab (swizzled).
// IN_MODE 0: fp32 X (stride K1), convert in staging (edge MLP -- saves the
//            separate f2bf pass, r13). IN_MODE 3: bf16 X, pure 16B copy.
// ---------------------------------------------------------------------------
template <int K1, int IN_MODE, int SLAB, int NKK>
__device__ __forceinline__ void stage_slab(
    int s, char* ab, int row0, int srow, int skk,
    const float* __restrict__ Xf, const unsigned short* __restrict__ Xb) {
#pragma unroll
  for (int c2 = 0; c2 < NKK; ++c2) {
    const int kloc = skk + 32 * c2;
    const int gk = s * SLAB + kloc;
    int off = srow * (2 * SLAB) + kloc * 2;
    off ^= (srow & 7) << 4;
    if (IN_MODE == 3) {
      u32x4 d = *(const u32x4*)(Xb + (size_t)(row0 + srow) * K1 + gk);
      *(u32x4*)(ab + off) = d;
    } else {
      const float* xp = Xf + (size_t)(row0 + srow) * K1 + gk;
      float4 A = *(const float4*)xp;
      float4 B = *(const float4*)(xp + 4);
      u32x4 pk = {cvtpk(A.x, A.y), cvtpk(A.z, A.w), cvtpk(B.x, B.y), cvtpk(B.z, B.w)};
      *(u32x4*)(ab + off) = pk;
    }
  }
}

// ---------------------------------------------------------------------------
// Fused 2-layer MLP: out = [relu?](relu(X @ W1 + b1) @ W2 + b2), N=256 cols.
// 64 rows x 256 cols per block, 4 waves (r6 structure -- best measured).
// Weights in FRAGMENT order (r11): wave's bq load = one coalesced 1KB block.
// LDS = 32KB union (a-slabs alias hidden; K=256 double-buffers two 16KB slabs).
// NOTE: no min-waves launch_bounds clause -- (256,5) forced spills (r5).
// r7: A-frags direct from global are uncoalesced -- keep LDS staging.
// r9: smaller tile regressed. r10: gather-in-staging regressed.
// ---------------------------------------------------------------------------
template <int K1, int IN_MODE>
__global__ __launch_bounds__(256) void fused_mlp2(
    const float* __restrict__ Xf, const unsigned short* __restrict__ Xb,
    const unsigned short* __restrict__ w1f, const float* __restrict__ b1,
    const unsigned short* __restrict__ w2f, const float* __restrict__ b2,
    unsigned short* __restrict__ out, int relu_out) {
  constexpr int SLAB  = (K1 < 128) ? K1 : 128;
  constexpr int NSLAB = K1 / SLAB;
  constexpr int NKK   = SLAB / 32;
  constexpr int KT1   = K1 / 32;
  __shared__ unsigned short h_lds[64 * 256];   // 32 KB: a-slabs + hidden + out
  char* hbase = (char*)h_lds;

  const int tid  = threadIdx.x;
  const int row0 = blockIdx.x * 64;
  const int lane = tid & 63;
  const int wid  = tid >> 6;
  const int lr   = lane & 15;
  const int kq   = lane >> 4;
  const int col0 = wid * 64;
  const int cb0  = wid * 4;     // 16-col block index of this wave's first tile
  const int bsub = lr & 3;
  const int asub = lr >> 2;
  const unsigned selT = (bsub & 1) ? 0x07060302u : 0x01000504u;

  const int srow = tid >> 2;
  const int skk  = (tid & 3) * 8;

  f32x4 acc[4][4];
#pragma unroll
  for (int m = 0; m < 4; ++m)
#pragma unroll
    for (int n = 0; n < 4; ++n) acc[m][n] = (f32x4){0.f, 0.f, 0.f, 0.f};

  float bias1[4];
#pragma unroll
  for (int n = 0; n < 4; ++n) bias1[n] = b1[col0 + n * 16 + lr];

  // ---------------- phase A: hidden = relu(X @ W1 + b1) ------------------
  stage_slab<K1, IN_MODE, SLAB, NKK>(0, hbase, row0, srow, skk, Xf, Xb);
  __syncthreads();

#pragma unroll
  for (int s = 0; s < NSLAB; ++s) {
    if (s + 1 < NSLAB)  // double-buffer: stage next slab into the other 16KB
      stage_slab<K1, IN_MODE, SLAB, NKK>(s + 1, hbase + 16384, row0, srow, skk,
                                         Xf, Xb);
    char* ab = hbase + (s & 1) * 16384;
#pragma unroll
    for (int kk = 0; kk < NKK; ++kk) {
      short8 af[4], bq[4];
#pragma unroll
      for (int m = 0; m < 4; ++m) {
        int r = m * 16 + lr;
        int off = r * (2 * SLAB) + kk * 64 + kq * 16;
        off ^= (r & 7) << 4;
        af[m] = *(short8*)(ab + off);
      }
      const int kt = s * NKK + kk;
#pragma unroll
      for (int n = 0; n < 4; ++n)
        bq[n] = *(const short8*)(w1f + ((size_t)(cb0 + n) * KT1 + kt) * 512 + lane * 8);
#pragma unroll
      for (int m = 0; m < 4; ++m)
#pragma unroll
        for (int n = 0; n < 4; ++n)
          acc[m][n] = __builtin_amdgcn_mfma_f32_16x16x32_bf16(af[m], bq[n], acc[m][n], 0, 0, 0);
    }
    __syncthreads();  // a-slab reads done (last iter: before epiA overwrites)
  }

  // epilogue A: bias + relu, 4x4 lane-transpose, 8B writes -> h layout
#pragma unroll
  for (int n = 0; n < 4; ++n) {
    float bn = bias1[n];
#pragma unroll
    for (int m = 0; m < 4; ++m) {
      float v0 = fmaxf(acc[m][n][0] + bn, 0.f);
      float v1 = fmaxf(acc[m][n][1] + bn, 0.f);
      float v2 = fmaxf(acc[m][n][2] + bn, 0.f);
      float v3 = fmaxf(acc[m][n][3] + bn, 0.f);
      unsigned W0 = cvtpk(v0, v1), W1 = cvtpk(v2, v3), T0, T1;
      xpose4(W0, W1, bsub, selT, T0, T1);
      int r = m * 16 + kq * 4 + bsub;
      int cb = col0 + n * 16 + asub * 4;
      int off = r * 512 + cb * 2;
      off ^= (r & 7) << 4;
      *(u32x2*)(hbase + off) = (u32x2){T0, T1};
    }
  }
  __syncthreads();

  // ---------------- phase B: out = hidden @ W2 + b2 ----------------------
#pragma unroll
  for (int m = 0; m < 4; ++m)
#pragma unroll
    for (int n = 0; n < 4; ++n) acc[m][n] = (f32x4){0.f, 0.f, 0.f, 0.f};

  float bias2[4];
#pragma unroll
  for (int n = 0; n < 4; ++n) bias2[n] = b2[col0 + n * 16 + lr];

#pragma unroll
  for (int ks = 0; ks < 8; ++ks) {
    short8 af[4], bq[4];
#pragma unroll
    for (int m = 0; m < 4; ++m) {
      int r = m * 16 + lr;
      int off = r * 512 + ks * 64 + kq * 16;
      off ^= (r & 7) << 4;
      af[m] = *(short8*)(hbase + off);
    }
#pragma unroll
    for (int n = 0; n < 4; ++n)
      bq[n] = *(const short8*)(w2f + ((size_t)(cb0 + n) * 8 + ks) * 512 + lane * 8);
#pragma unroll
    for (int m = 0; m < 4; ++m)
#pragma unroll
      for (int n = 0; n < 4; ++n)
        acc[m][n] = __builtin_amdgcn_mfma_f32_16x16x32_bf16(af[m], bq[n], acc[m][n], 0, 0, 0);
  }
  __syncthreads();  // all waves done READING h_lds before overwrite

  // epilogue B: bias (+relu), transpose, write tile into h_lds
#pragma unroll
  for (int n = 0; n < 4; ++n) {
    float bn = bias2[n];
#pragma unroll
    for (int m = 0; m < 4; ++m) {
      float v0 = acc[m][n][0] + bn;
      float v1 = acc[m][n][1] + bn;
      float v2 = acc[m][n][2] + bn;
      float v3 = acc[m][n][3] + bn;
      if (relu_out) {
        v0 = fmaxf(v0, 0.f); v1 = fmaxf(v1, 0.f);
        v2 = fmaxf(v2, 0.f); v3 = fmaxf(v3, 0.f);
      }
      unsigned W0 = cvtpk(v0, v1), W1 = cvtpk(v2, v3), T0, T1;
      xpose4(W0, W1, bsub, selT, T0, T1);
      int r = m * 16 + kq * 4 + bsub;
      int cb = col0 + n * 16 + asub * 4;
      int off = r * 512 + cb * 2;
      off ^= (r & 7) << 4;
      *(u32x2*)(hbase + off) = (u32x2){T0, T1};
    }
  }
  __syncthreads();

  // coalesced copy h_lds -> out: each half-wave writes one full 512B row
#pragma unroll
  for (int it = 0; it < 8; ++it) {
    int r = (tid >> 5) + it * 8;
    int byte = (tid & 31) * 16;
    int off = (r * 512 + byte) ^ ((r & 7) << 4);
    u32x4 d = *(u32x4*)(hbase + off);
    *(u32x4*)((char*)out + (size_t)(row0 + r) * 512 + byte) = d;
  }
}

// ---------------------------------------------------------------------------
// CSR build: rp = degree hist -> (scan+fill) per-node END offsets.
// ---------------------------------------------------------------------------
__global__ void hist_deg(const int* __restrict__ dst, int* __restrict__ rp) {
  int e = blockIdx.x * 256 + threadIdx.x;
  if (e < N_EDGES) atomicAdd(&rp[dst[e]], 1);
}

__global__ __launch_bounds__(256) void scan_block(int* __restrict__ rp,
                                                  int* __restrict__ bsum) {
  __shared__ int ts[256];
  int b = blockIdx.x, t = threadIdx.x;
  int base = b * 2048 + t * 8;
  int v[8]; int s = 0;
#pragma unroll
  for (int i = 0; i < 8; ++i) {
    int idx = base + i;
    v[i] = (idx < N_NODES) ? rp[idx] : 0;
    s += v[i];
  }
  ts[t] = s;
  __syncthreads();
#pragma unroll
  for (int off = 1; off < 256; off <<= 1) {
    int add = (t >= off) ? ts[t - off] : 0;
    __syncthreads();
    ts[t] += add;
    __syncthreads();
  }
  int excl = ts[t] - s;
  if (t == 255) bsum[b] = ts[255];
  int run = excl;
#pragma unroll
  for (int i = 0; i < 8; ++i) {
    int idx = base + i;
    if (idx < N_NODES) rp[idx] = run;
    run += v[i];
  }
}

__global__ __launch_bounds__(256) void scan_bsum(int* __restrict__ bsum, int nb) {
  __shared__ int ts[256];
  int t = threadIdx.x;
  int v = (t < nb) ? bsum[t] : 0;
  ts[t] = v;
  __syncthreads();
#pragma unroll
  for (int off = 1; off < 256; off <<= 1) {
    int add = (t >= off) ? ts[t - off] : 0;
    __syncthreads();
    ts[t] += add;
    __syncthreads();
  }
  if (t < nb) bsum[t] = ts[t] - v;  // exclusive
}

__global__ void scan_add(int* __restrict__ rp, const int* __restrict__ bsum) {
  int i = blockIdx.x * 256 + threadIdx.x;
  if (i < N_NODES) rp[i] += bsum[i >> 11];
}

__global__ void csr_fill(const int* __restrict__ src, const int* __restrict__ dst,
                         int* __restrict__ rp, int2* __restrict__ csr) {
  int e = blockIdx.x * 256 + threadIdx.x;
  if (e >= N_EDGES) return;
  int d = dst[e];
  int p = atomicAdd(&rp[d], 1);
  csr[p] = make_int2(src[e], e);
}

// ---------------------------------------------------------------------------
// Gather-aggregate: agg[v] = x_v + sum_{e: dst(e)=v} relu(x_src + ea_e)
// (self-term absorbed here so the conv MLP staging is a pure copy).
// One wave per node, 4 cols/lane, 4-edge unroll for more loads in flight.
// ---------------------------------------------------------------------------
__global__ __launch_bounds__(256) void gather_agg(
    const unsigned short* __restrict__ ea, const unsigned short* __restrict__ xb,
    const int* __restrict__ rp, const int2* __restrict__ csr,
    unsigned short* __restrict__ agg) {
  int v = blockIdx.x * 4 + (threadIdx.x >> 6);
  if (v >= N_NODES) return;
  int lane = threadIdx.x & 63;
  int c = lane * 4;
  int beg = (v == 0) ? 0 : rp[v - 1];
  int end = rp[v];
  ushort4 sv = *(const ushort4*)(xb + (size_t)v * 256 + c);
  float a0 = bf2f(sv.x), a1 = bf2f(sv.y), a2 = bf2f(sv.z), a3 = bf2f(sv.w);
  int i = beg;
  for (; i + 4 <= end; i += 4) {
    int2 s0 = csr[i], s1 = csr[i + 1], s2 = csr[i + 2], s3 = csr[i + 3];
    ushort4 e0 = *(const ushort4*)(ea + (size_t)s0.y * 256 + c);
    ushort4 e1 = *(const ushort4*)(ea + (size_t)s1.y * 256 + c);
    ushort4 e2 = *(const ushort4*)(ea + (size_t)s2.y * 256 + c);
    ushort4 e3 = *(const ushort4*)(ea + (size_t)s3.y * 256 + c);
    ushort4 h0 = *(const ushort4*)(xb + (size_t)s0.x * 256 + c);
    ushort4 h1 = *(const ushort4*)(xb + (size_t)s1.x * 256 + c);
    ushort4 h2 = *(const ushort4*)(xb + (size_t)s2.x * 256 + c);
    ushort4 h3 = *(const ushort4*)(xb + (size_t)s3.x * 256 + c);
    a0 += fmaxf(bf2f(h0.x) + bf2f(e0.x), 0.f) + fmaxf(bf2f(h1.x) + bf2f(e1.x), 0.f)
        + fmaxf(bf2f(h2.x) + bf2f(e2.x), 0.f) + fmaxf(bf2f(h3.x) + bf2f(e3.x), 0.f);
    a1 += fmaxf(bf2f(h0.y) + bf2f(e0.y), 0.f) + fmaxf(bf2f(h1.y) + bf2f(e1.y), 0.f)
        + fmaxf(bf2f(h2.y) + bf2f(e2.y), 0.f) + fmaxf(bf2f(h3.y) + bf2f(e3.y), 0.f);
    a2 += fmaxf(bf2f(h0.z) + bf2f(e0.z), 0.f) + fmaxf(bf2f(h1.z) + bf2f(e1.z), 0.f)
        + fmaxf(bf2f(h2.z) + bf2f(e2.z), 0.f) + fmaxf(bf2f(h3.z) + bf2f(e3.z), 0.f);
    a3 += fmaxf(bf2f(h0.w) + bf2f(e0.w), 0.f) + fmaxf(bf2f(h1.w) + bf2f(e1.w), 0.f)
        + fmaxf(bf2f(h2.w) + bf2f(e2.w), 0.f) + fmaxf(bf2f(h3.w) + bf2f(e3.w), 0.f);
  }
  for (; i < end; ++i) {
    int2 se = csr[i];
    ushort4 ev = *(const ushort4*)(ea + (size_t)se.y * 256 + c);
    ushort4 hv = *(const ushort4*)(xb + (size_t)se.x * 256 + c);
    a0 += fmaxf(bf2f(hv.x) + bf2f(ev.x), 0.f);
    a1 += fmaxf(bf2f(hv.y) + bf2f(ev.y), 0.f);
    a2 += fmaxf(bf2f(hv.z) + bf2f(ev.z), 0.f);
    a3 += fmaxf(bf2f(hv.w) + bf2f(ev.w), 0.f);
  }
  u32x2 pk = {cvtpk(a0, a1), cvtpk(a2, a3)};
  *(u32x2*)(agg + (size_t)v * 256 + c) = pk;
}

// ---------------------------------------------------------------------------
// Pool: mean of h2 rows per graph; 4 rows in flight, ushort4 loads.
// ---------------------------------------------------------------------------
__global__ __launch_bounds__(256) void pool_mean(const unsigned short* __restrict__ h2,
                                                 const int* __restrict__ batch,
                                                 float* __restrict__ pooled) {
  int g = blockIdx.x;
  int tid = threadIdx.x;
  int lane = tid & 63;   // col group (4 cols)
  int sub = tid >> 6;    // row offset 0..3
  int lo = 0, hi = N_NODES;
  while (lo < hi) { int mid = (lo + hi) >> 1; if (batch[mid] < g) lo = mid + 1; else hi = mid; }
  int start = lo;
  hi = N_NODES;
  while (lo < hi) { int mid = (lo + hi) >> 1; if (batch[mid] < g + 1) lo = mid + 1; else hi = mid; }
  int end = lo;
  float s0 = 0.f, s1 = 0.f, s2 = 0.f, s3 = 0.f;
  for (int r = start + sub; r < end; r += 4) {
    ushort4 hv = *(const ushort4*)(h2 + (size_t)r * 256 + lane * 4);
    s0 += bf2f(hv.x); s1 += bf2f(hv.y); s2 += bf2f(hv.z); s3 += bf2f(hv.w);
  }
  __shared__ float4 red[4][64];
  red[sub][lane] = make_float4(s0, s1, s2, s3);
  __syncthreads();
  if (sub == 0) {
    float4 a = red[0][lane], b = red[1][lane], cc = red[2][lane], d = red[3][lane];
    float inv = 1.0f / fmaxf((float)(end - start), 1.0f);
    float4 t = make_float4((a.x + b.x + cc.x + d.x) * inv,
                           (a.y + b.y + cc.y + d.y) * inv,
                           (a.z + b.z + cc.z + d.z) * inv,
                           (a.w + b.w + cc.w + d.w) * inv);
    *(float4*)(pooled + (size_t)g * 256 + lane * 4) = t;
  }
}

// ---------------------------------------------------------------------------
// Heads: g1=relu(p@l1+b) [128], g2=relu(g1@l2+b) [64], 3 dot-products
// ---------------------------------------------------------------------------
__global__ __launch_bounds__(128) void head_mlp(
    const float* __restrict__ pooled, const float* __restrict__ l1w,
    const float* __restrict__ l1b, const float* __restrict__ l2w,
    const float* __restrict__ l2b, const float* __restrict__ hSw,
    const float* __restrict__ hSb, const float* __restrict__ hPw,
    const float* __restrict__ hPb, const float* __restrict__ hNw,
    const float* __restrict__ hNb, float* __restrict__ out) {
  int g = blockIdx.x, tid = threadIdx.x;
  __shared__ float p[256];
  __shared__ float g1[128];
  __shared__ float g2[64];
  p[tid] = pooled[(size_t)g * 256 + tid];
  p[tid + 128] = pooled[(size_t)g * 256 + tid + 128];
  __syncthreads();
  float a = l1b[tid];
#pragma unroll 8
  for (int k = 0; k < 256; ++k) a += p[k] * l1w[k * 128 + tid];
  g1[tid] = fmaxf(a, 0.f);
  __syncthreads();
  if (tid < 64) {
    float b = l2b[tid];
#pragma unroll 8
    for (int k = 0; k < 128; ++k) b += g1[k] * l2w[k * 64 + tid];
    g2[tid] = fmaxf(b, 0.f);
  }
  __syncthreads();
  if (tid < 64) {
    float v = g2[tid];
    float s = v * hSw[tid], pq = v * hPw[tid], nq = v * hNw[tid];
#pragma unroll
    for (int off = 32; off > 0; off >>= 1) {
      s  += __shfl_down(s, off);
      pq += __shfl_down(pq, off);
      nq += __shfl_down(nq, off);
    }
    if (tid == 0) {
      out[g]                = s  + hSb[0];
      out[N_GRAPHS + g]     = pq + hPb[0];
      out[2 * N_GRAPHS + g] = nq + hNb[0];
    }
  }
}

// ---------------------------------------------------------------------------
extern "C" void kernel_launch(void* const* d_in, const int* in_sizes, int n_in,
                              void* d_out, int out_size, void* d_ws, size_t ws_size,
                              hipStream_t stream) {
  const float* x         = (const float*)d_in[0];
  const float* edge_attr = (const float*)d_in[1];
  const int*   ei        = (const int*)d_in[2];
  const int*   batch     = (const int*)d_in[3];
  const float* em_w1 = (const float*)d_in[4];  const float* em_b1 = (const float*)d_in[5];
  const float* em_w2 = (const float*)d_in[6];  const float* em_b2 = (const float*)d_in[7];
  const float* c1_w1 = (const float*)d_in[8];  const float* c1_b1 = (const float*)d_in[9];
  const float* c1_w2 = (const float*)d_in[10]; const float* c1_b2 = (const float*)d_in[11];
  const float* c2_w1 = (const float*)d_in[12]; const float* c2_b1 = (const float*)d_in[13];
  const float* c2_w2 = (const float*)d_in[14]; const float* c2_b2 = (const float*)d_in[15];
  const float* l1_w = (const float*)d_in[16];  const float* l1_b = (const float*)d_in[17];
  const float* l2_w = (const float*)d_in[18];  const float* l2_b = (const float*)d_in[19];
  const float* hS_w = (const float*)d_in[20];  const float* hS_b = (const float*)d_in[21];
  const float* hP_w = (const float*)d_in[22];  const float* hP_b = (const float*)d_in[23];
  const float* hN_w = (const float*)d_in[24];  const float* hN_b = (const float*)d_in[25];

  char* ws = (char*)d_ws;
  // layout (bytes):
  //   ea   @ 0           : E*256*2 = 409,600,000  (bf16, edge order; h2 later)
  //   agg  @ 409,600,000 : N*256*2 = 102,400,000  (bf16, MLP-ready: + self)
  //   xb   @ 512,000,000 : N*256*2 = 102,400,000  (bf16 copy of x)
  //   h1   @ 614,400,000 : N*256*2 = 102,400,000
  //   pool @ 716,800,000 : G*256*4 =   8,192,000  <- csr/rp/bsum alias
  //   wts  @ 724,992,000 : ~688,128 (fragment-ordered)
  unsigned short* ea     = (unsigned short*)ws;
  unsigned short* agg    = (unsigned short*)(ws + 409600000);
  unsigned short* xb     = (unsigned short*)(ws + 512000000);
  unsigned short* h1     = (unsigned short*)(ws + 614400000);
  unsigned short* h2     = ea;  // alias: ea dead after 2nd gather
  float*          pooled = (float*)(ws + 716800000);
  int2*           csr    = (int2*)(ws + 716800000);            // 6,400,000 B
  int*            rp     = (int*)(ws + 723200000);             //   800,000 B
  int*            bsum   = (int*)(ws + 724000000);             //     1,024 B
  unsigned short* wt     = (unsigned short*)(ws + 724992000);
  unsigned short* em_w1f = wt;                 // 256 x 64
  unsigned short* em_w2f = em_w1f + 16384;     // 256 x 256
  unsigned short* c1_w1f = em_w2f + 65536;
  unsigned short* c1_w2f = c1_w1f + 65536;
  unsigned short* c2_w1f = c1_w2f + 65536;
  unsigned short* c2_w2f = c2_w1f + 65536;

  const int* srcI = ei;
  const int* dstI = ei + N_EDGES;

  wtrans_frag<<<(16384 + 255) / 256, 256, 0, stream>>>(em_w1, em_w1f, 64, 256);
  wtrans_frag<<<(65536 + 255) / 256, 256, 0, stream>>>(em_w2, em_w2f, 256, 256);
  wtrans_frag<<<(65536 + 255) / 256, 256, 0, stream>>>(c1_w1, c1_w1f, 256, 256);
  wtrans_frag<<<(65536 + 255) / 256, 256, 0, stream>>>(c1_w2, c1_w2f, 256, 256);
  wtrans_frag<<<(65536 + 255) / 256, 256, 0, stream>>>(c2_w1, c2_w1f, 256, 256);
  wtrans_frag<<<(65536 + 255) / 256, 256, 0, stream>>>(c2_w2, c2_w2f, 256, 256);

  // bf16 table: x (node features) -- edge_attr now staged fp32-direct (r13)
  f2bf_bulk<<<(N_NODES * 256 / 8 + 255) / 256, 256, 0, stream>>>(x, xb, N_NODES * 256 / 8);

  // CSR build (by dst)
  hipMemsetAsync(rp, 0, (size_t)N_NODES * 4, stream);
  hist_deg<<<(N_EDGES + 255) / 256, 256, 0, stream>>>(dstI, rp);
  scan_block<<<(N_NODES + 2047) / 2048, 256, 0, stream>>>(rp, bsum);
  scan_bsum<<<1, 256, 0, stream>>>(bsum, (N_NODES + 2047) / 2048);
  scan_add<<<(N_NODES + 255) / 256, 256, 0, stream>>>(rp, bsum);
  csr_fill<<<N_EDGES / 256, 256, 0, stream>>>(srcI, dstI, rp, csr);

  // ea = edge MLP directly from fp32 edge_attr (no output relu)
  fused_mlp2<64, 0><<<N_EDGES / 64, 256, 0, stream>>>(
      edge_attr, nullptr, em_w1f, em_b1, em_w2f, em_b2, ea, 0);

  // conv1: gather (with self-term) -> pure-copy-staged MLP
  gather_agg<<<(N_NODES + 3) / 4, 256, 0, stream>>>(ea, xb, rp, csr, agg);
  fused_mlp2<256, 3><<<N_NODES / 64, 256, 0, stream>>>(
      nullptr, agg, c1_w1f, c1_b1, c1_w2f, c1_b2, h1, 1);

  // conv2
  gather_agg<<<(N_NODES + 3) / 4, 256, 0, stream>>>(ea, h1, rp, csr, agg);
  fused_mlp2<256, 3><<<N_NODES / 64, 256, 0, stream>>>(
      nullptr, agg, c2_w1f, c2_b1, c2_w2f, c2_b2, h2, 1);

  // pool + heads
  pool_mean<<<N_GRAPHS, 256, 0, stream>>>(h2, batch, pooled);
  head_mlp<<<N_GRAPHS, 128, 0, stream>>>(pooled, l1_w, l1_b, l2_w, l2_b,
                                         hS_w, hS_b, hP_w, hP_b, hN_w, hN_b,
                                         (float*)d_out);
}

// Round 14
// 1004.260 us; speedup vs baseline: 1.0578x; 1.0084x over previous
//
#include <hip/hip_runtime.h>
#include <hip/hip_bf16.h>

typedef __attribute__((ext_vector_type(8))) short short8;
typedef __attribute__((ext_vector_type(4))) float f32x4;
typedef __attribute__((ext_vector_type(2))) unsigned int u32x2;
typedef __attribute__((ext_vector_type(4))) unsigned int u32x4;

#define N_NODES  200000
#define N_EDGES  800000
#define N_GRAPHS 8000

__device__ __forceinline__ unsigned short f2bf(float f) {
  unsigned int u = __float_as_uint(f);
  unsigned int r = (u + 0x7fffu + ((u >> 16) & 1u)) >> 16;
  return (unsigned short)r;
}
__device__ __forceinline__ float bf2f(unsigned short s) {
  return __uint_as_float(((unsigned int)s) << 16);
}
// pack 2 fp32 -> u32 of 2 bf16 via v_cvt_pk_bf16_f32
__device__ __forceinline__ unsigned cvtpk(float a, float b) {
  union { __hip_bfloat162 h; unsigned u; } cv;
  cv.h = __float22bfloat162_rn(make_float2(a, b));
  return cv.u;
}

// 4x4 bf16 transpose across 4 lanes (lanes differing in bits 0,1).
__device__ __forceinline__ void xpose4(unsigned W0, unsigned W1, int bsub,
                                       unsigned selT, unsigned& T0, unsigned& T1) {
  unsigned t0 = (unsigned)__shfl_xor((int)W0, 2);
  unsigned t1 = (unsigned)__shfl_xor((int)W1, 2);
  unsigned A0 = (bsub & 2) ? t1 : W0;
  unsigned A1 = (bsub & 2) ? W1 : t0;
  unsigned t2 = (unsigned)__shfl_xor((int)A0, 1);
  unsigned t3 = (unsigned)__shfl_xor((int)A1, 1);
  T0 = __builtin_amdgcn_perm(A0, t2, selT);
  T1 = __builtin_amdgcn_perm(A1, t3, selT);
}

// ---------------------------------------------------------------------------
// Fragment-order weight convert (r11 win: +35% on edge MLP), ALL 6 matrices
// in ONE launch (r14). wf[(((c>>4)*KT + kt)*64 + lane)*8 + j] =
// w[kt*32 + (lane>>4)*8 + j][c], c = cb*16 + (lane&15), KT = K/32.
// ---------------------------------------------------------------------------
__device__ __forceinline__ void wfrag_one(const float* w, unsigned short* wf,
                                          int id, int K, int Nc) {
  int j    = id & 7;
  int lane = (id >> 3) & 63;
  int rest = id >> 9;            // cb*KT + kt
  int KT   = K >> 5;
  int kt   = rest % KT;
  int cb   = rest / KT;
  int c = cb * 16 + (lane & 15);
  int k = kt * 32 + (lane >> 4) * 8 + j;
  wf[id] = f2bf(w[k * Nc + c]);
}

__global__ __launch_bounds__(256) void wtrans_all(
    const float* __restrict__ em_w1, const float* __restrict__ em_w2,
    const float* __restrict__ c1_w1, const float* __restrict__ c1_w2,
    const float* __restrict__ c2_w1, const float* __restrict__ c2_w2,
    unsigned short* __restrict__ wf_base) {
  int id = blockIdx.x * 256 + threadIdx.x;
  if (id < 16384) {
    wfrag_one(em_w1, wf_base, id, 64, 256);                      // em_w1f @ 0
    return;
  }
  int idx = id - 16384;
  int m = idx >> 16;           // 0..4
  int within = idx & 65535;
  if (m > 4) return;
  const float* src = (m == 0) ? em_w2 : (m == 1) ? c1_w1 : (m == 2) ? c1_w2
                   : (m == 3) ? c2_w1 : c2_w2;
  wfrag_one(src, wf_base + 16384 + m * 65536, within, 256, 256);
}

// fp32 -> bf16 bulk convert (8 elems/thread)
__global__ __launch_bounds__(256) void f2bf_bulk(const float* __restrict__ x,
                                                 unsigned short* __restrict__ xb,
                                                 int n8) {
  int id = blockIdx.x * 256 + threadIdx.x;
  if (id >= n8) return;
  float4 a = ((const float4*)x)[id * 2];
  float4 b = ((const float4*)x)[id * 2 + 1];
  u32x4 pk = {cvtpk(a.x, a.y), cvtpk(a.z, a.w), cvtpk(b.x, b.y), cvtpk(b.z, b.w)};
  ((u32x4*)xb)[id] = pk;
}

// ---------------------------------------------------------------------------
// Staging: slab s of the 64-row input tile -> bf16 into ab (swizzled).
// IN_MODE 0: fp32 X (stride K1), convert in staging (edge MLP).
// IN_MODE 3: bf16 X, pure 16B copy (convs: agg is MLP-ready).
// ---------------------------------------------------------------------------
template <int K1, int IN_MODE, int SLAB, int NKK>
__device__ __forceinline__ void stage_slab(
    int s, char* ab, int row0, int srow, int skk,
    const float* __restrict__ Xf, const unsigned short* __restrict__ Xb) {
#pragma unroll
  for (int c2 = 0; c2 < NKK; ++c2) {
    const int kloc = skk + 32 * c2;
    const int gk = s * SLAB + kloc;
    int off = srow * (2 * SLAB) + kloc * 2;
    off ^= (srow & 7) << 4;
    if (IN_MODE == 3) {
      u32x4 d = *(const u32x4*)(Xb + (size_t)(row0 + srow) * K1 + gk);
      *(u32x4*)(ab + off) = d;
    } else {
      const float* xp = Xf + (size_t)(row0 + srow) * K1 + gk;
      float4 A = *(const float4*)xp;
      float4 B = *(const float4*)(xp + 4);
      u32x4 pk = {cvtpk(A.x, A.y), cvtpk(A.z, A.w), cvtpk(B.x, B.y), cvtpk(B.z, B.w)};
      *(u32x4*)(ab + off) = pk;
    }
  }
}

// ---------------------------------------------------------------------------
// Fused 2-layer MLP: out = [relu?](relu(X @ W1 + b1) @ W2 + b2), N=256 cols.
// 64 rows x 256 cols per block, 4 waves (r6 structure -- best measured).
// Weights in FRAGMENT order (r11): wave's bq load = one coalesced 1KB block.
// LDS = 32KB union (a-slabs alias hidden; K=256 double-buffers two 16KB slabs).
// NOTE: no min-waves launch_bounds clause -- (256,5) forced spills (r5).
// r7: A-frags direct from global are uncoalesced -- keep LDS staging.
// r9: smaller tile regressed. r10: gather-in-staging regressed.
// ---------------------------------------------------------------------------
template <int K1, int IN_MODE>
__global__ __launch_bounds__(256) void fused_mlp2(
    const float* __restrict__ Xf, const unsigned short* __restrict__ Xb,
    const unsigned short* __restrict__ w1f, const float* __restrict__ b1,
    const unsigned short* __restrict__ w2f, const float* __restrict__ b2,
    unsigned short* __restrict__ out, int relu_out) {
  constexpr int SLAB  = (K1 < 128) ? K1 : 128;
  constexpr int NSLAB = K1 / SLAB;
  constexpr int NKK   = SLAB / 32;
  constexpr int KT1   = K1 / 32;
  __shared__ unsigned short h_lds[64 * 256];   // 32 KB: a-slabs + hidden + out
  char* hbase = (char*)h_lds;

  const int tid  = threadIdx.x;
  const int row0 = blockIdx.x * 64;
  const int lane = tid & 63;
  const int wid  = tid >> 6;
  const int lr   = lane & 15;
  const int kq   = lane >> 4;
  const int col0 = wid * 64;
  const int cb0  = wid * 4;     // 16-col block index of this wave's first tile
  const int bsub = lr & 3;
  const int asub = lr >> 2;
  const unsigned selT = (bsub & 1) ? 0x07060302u : 0x01000504u;

  const int srow = tid >> 2;
  const int skk  = (tid & 3) * 8;

  f32x4 acc[4][4];
#pragma unroll
  for (int m = 0; m < 4; ++m)
#pragma unroll
    for (int n = 0; n < 4; ++n) acc[m][n] = (f32x4){0.f, 0.f, 0.f, 0.f};

  float bias1[4];
#pragma unroll
  for (int n = 0; n < 4; ++n) bias1[n] = b1[col0 + n * 16 + lr];

  // ---------------- phase A: hidden = relu(X @ W1 + b1) ------------------
  stage_slab<K1, IN_MODE, SLAB, NKK>(0, hbase, row0, srow, skk, Xf, Xb);
  __syncthreads();

#pragma unroll
  for (int s = 0; s < NSLAB; ++s) {
    if (s + 1 < NSLAB)  // double-buffer: stage next slab into the other 16KB
      stage_slab<K1, IN_MODE, SLAB, NKK>(s + 1, hbase + 16384, row0, srow, skk,
                                         Xf, Xb);
    char* ab = hbase + (s & 1) * 16384;
#pragma unroll
    for (int kk = 0; kk < NKK; ++kk) {
      short8 af[4], bq[4];
#pragma unroll
      for (int m = 0; m < 4; ++m) {
        int r = m * 16 + lr;
        int off = r * (2 * SLAB) + kk * 64 + kq * 16;
        off ^= (r & 7) << 4;
        af[m] = *(short8*)(ab + off);
      }
      const int kt = s * NKK + kk;
#pragma unroll
      for (int n = 0; n < 4; ++n)
        bq[n] = *(const short8*)(w1f + ((size_t)(cb0 + n) * KT1 + kt) * 512 + lane * 8);
#pragma unroll
      for (int m = 0; m < 4; ++m)
#pragma unroll
        for (int n = 0; n < 4; ++n)
          acc[m][n] = __builtin_amdgcn_mfma_f32_16x16x32_bf16(af[m], bq[n], acc[m][n], 0, 0, 0);
    }
    __syncthreads();  // a-slab reads done (last iter: before epiA overwrites)
  }

  // epilogue A: bias + relu, 4x4 lane-transpose, 8B writes -> h layout
#pragma unroll
  for (int n = 0; n < 4; ++n) {
    float bn = bias1[n];
#pragma unroll
    for (int m = 0; m < 4; ++m) {
      float v0 = fmaxf(acc[m][n][0] + bn, 0.f);
      float v1 = fmaxf(acc[m][n][1] + bn, 0.f);
      float v2 = fmaxf(acc[m][n][2] + bn, 0.f);
      float v3 = fmaxf(acc[m][n][3] + bn, 0.f);
      unsigned W0 = cvtpk(v0, v1), W1 = cvtpk(v2, v3), T0, T1;
      xpose4(W0, W1, bsub, selT, T0, T1);
      int r = m * 16 + kq * 4 + bsub;
      int cb = col0 + n * 16 + asub * 4;
      int off = r * 512 + cb * 2;
      off ^= (r & 7) << 4;
      *(u32x2*)(hbase + off) = (u32x2){T0, T1};
    }
  }
  __syncthreads();

  // ---------------- phase B: out = hidden @ W2 + b2 ----------------------
#pragma unroll
  for (int m = 0; m < 4; ++m)
#pragma unroll
    for (int n = 0; n < 4; ++n) acc[m][n] = (f32x4){0.f, 0.f, 0.f, 0.f};

  float bias2[4];
#pragma unroll
  for (int n = 0; n < 4; ++n) bias2[n] = b2[col0 + n * 16 + lr];

#pragma unroll
  for (int ks = 0; ks < 8; ++ks) {
    short8 af[4], bq[4];
#pragma unroll
    for (int m = 0; m < 4; ++m) {
      int r = m * 16 + lr;
      int off = r * 512 + ks * 64 + kq * 16;
      off ^= (r & 7) << 4;
      af[m] = *(short8*)(hbase + off);
    }
#pragma unroll
    for (int n = 0; n < 4; ++n)
      bq[n] = *(const short8*)(w2f + ((size_t)(cb0 + n) * 8 + ks) * 512 + lane * 8);
#pragma unroll
    for (int m = 0; m < 4; ++m)
#pragma unroll
      for (int n = 0; n < 4; ++n)
        acc[m][n] = __builtin_amdgcn_mfma_f32_16x16x32_bf16(af[m], bq[n], acc[m][n], 0, 0, 0);
  }
  __syncthreads();  // all waves done READING h_lds before overwrite

  // epilogue B: bias (+relu), transpose, write tile into h_lds
#pragma unroll
  for (int n = 0; n < 4; ++n) {
    float bn = bias2[n];
#pragma unroll
    for (int m = 0; m < 4; ++m) {
      float v0 = acc[m][n][0] + bn;
      float v1 = acc[m][n][1] + bn;
      float v2 = acc[m][n][2] + bn;
      float v3 = acc[m][n][3] + bn;
      if (relu_out) {
        v0 = fmaxf(v0, 0.f); v1 = fmaxf(v1, 0.f);
        v2 = fmaxf(v2, 0.f); v3 = fmaxf(v3, 0.f);
      }
      unsigned W0 = cvtpk(v0, v1), W1 = cvtpk(v2, v3), T0, T1;
      xpose4(W0, W1, bsub, selT, T0, T1);
      int r = m * 16 + kq * 4 + bsub;
      int cb = col0 + n * 16 + asub * 4;
      int off = r * 512 + cb * 2;
      off ^= (r & 7) << 4;
      *(u32x2*)(hbase + off) = (u32x2){T0, T1};
    }
  }
  __syncthreads();

  // coalesced copy h_lds -> out: each half-wave writes one full 512B row
#pragma unroll
  for (int it = 0; it < 8; ++it) {
    int r = (tid >> 5) + it * 8;
    int byte = (tid & 31) * 16;
    int off = (r * 512 + byte) ^ ((r & 7) << 4);
    u32x4 d = *(u32x4*)(hbase + off);
    *(u32x4*)((char*)out + (size_t)(row0 + r) * 512 + byte) = d;
  }
}

// ---------------------------------------------------------------------------
// CSR build: rp = degree hist -> (scan+fill) per-node END offsets.
// ---------------------------------------------------------------------------
__global__ void hist_deg(const int* __restrict__ dst, int* __restrict__ rp) {
  int e = blockIdx.x * 256 + threadIdx.x;
  if (e < N_EDGES) atomicAdd(&rp[dst[e]], 1);
}

__global__ __launch_bounds__(256) void scan_block(int* __restrict__ rp,
                                                  int* __restrict__ bsum) {
  __shared__ int ts[256];
  int b = blockIdx.x, t = threadIdx.x;
  int base = b * 2048 + t * 8;
  int v[8]; int s = 0;
#pragma unroll
  for (int i = 0; i < 8; ++i) {
    int idx = base + i;
    v[i] = (idx < N_NODES) ? rp[idx] : 0;
    s += v[i];
  }
  ts[t] = s;
  __syncthreads();
#pragma unroll
  for (int off = 1; off < 256; off <<= 1) {
    int add = (t >= off) ? ts[t - off] : 0;
    __syncthreads();
    ts[t] += add;
    __syncthreads();
  }
  int excl = ts[t] - s;
  if (t == 255) bsum[b] = ts[255];
  int run = excl;
#pragma unroll
  for (int i = 0; i < 8; ++i) {
    int idx = base + i;
    if (idx < N_NODES) rp[idx] = run;
    run += v[i];
  }
}

__global__ __launch_bounds__(256) void scan_bsum(int* __restrict__ bsum, int nb) {
  __shared__ int ts[256];
  int t = threadIdx.x;
  int v = (t < nb) ? bsum[t] : 0;
  ts[t] = v;
  __syncthreads();
#pragma unroll
  for (int off = 1; off < 256; off <<= 1) {
    int add = (t >= off) ? ts[t - off] : 0;
    __syncthreads();
    ts[t] += add;
    __syncthreads();
  }
  if (t < nb) bsum[t] = ts[t] - v;  // exclusive
}

__global__ void scan_add(int* __restrict__ rp, const int* __restrict__ bsum) {
  int i = blockIdx.x * 256 + threadIdx.x;
  if (i < N_NODES) rp[i] += bsum[i >> 11];
}

__global__ void csr_fill(const int* __restrict__ src, const int* __restrict__ dst,
                         int* __restrict__ rp, int2* __restrict__ csr) {
  int e = blockIdx.x * 256 + threadIdx.x;
  if (e >= N_EDGES) return;
  int d = dst[e];
  int p = atomicAdd(&rp[d], 1);
  csr[p] = make_int2(src[e], e);
}

// ---------------------------------------------------------------------------
// Gather-aggregate: agg[v] = x_v + sum_{e: dst(e)=v} relu(x_src + ea_e)
// (self-term absorbed here so the conv MLP staging is a pure copy).
// One wave per node, 4 cols/lane, 4-edge unroll for more loads in flight.
// ---------------------------------------------------------------------------
__global__ __launch_bounds__(256) void gather_agg(
    const unsigned short* __restrict__ ea, const unsigned short* __restrict__ xb,
    const int* __restrict__ rp, const int2* __restrict__ csr,
    unsigned short* __restrict__ agg) {
  int v = blockIdx.x * 4 + (threadIdx.x >> 6);
  if (v >= N_NODES) return;
  int lane = threadIdx.x & 63;
  int c = lane * 4;
  int beg = (v == 0) ? 0 : rp[v - 1];
  int end = rp[v];
  ushort4 sv = *(const ushort4*)(xb + (size_t)v * 256 + c);
  float a0 = bf2f(sv.x), a1 = bf2f(sv.y), a2 = bf2f(sv.z), a3 = bf2f(sv.w);
  int i = beg;
  for (; i + 4 <= end; i += 4) {
    int2 s0 = csr[i], s1 = csr[i + 1], s2 = csr[i + 2], s3 = csr[i + 3];
    ushort4 e0 = *(const ushort4*)(ea + (size_t)s0.y * 256 + c);
    ushort4 e1 = *(const ushort4*)(ea + (size_t)s1.y * 256 + c);
    ushort4 e2 = *(const ushort4*)(ea + (size_t)s2.y * 256 + c);
    ushort4 e3 = *(const ushort4*)(ea + (size_t)s3.y * 256 + c);
    ushort4 h0 = *(const ushort4*)(xb + (size_t)s0.x * 256 + c);
    ushort4 h1 = *(const ushort4*)(xb + (size_t)s1.x * 256 + c);
    ushort4 h2 = *(const ushort4*)(xb + (size_t)s2.x * 256 + c);
    ushort4 h3 = *(const ushort4*)(xb + (size_t)s3.x * 256 + c);
    a0 += fmaxf(bf2f(h0.x) + bf2f(e0.x), 0.f) + fmaxf(bf2f(h1.x) + bf2f(e1.x), 0.f)
        + fmaxf(bf2f(h2.x) + bf2f(e2.x), 0.f) + fmaxf(bf2f(h3.x) + bf2f(e3.x), 0.f);
    a1 += fmaxf(bf2f(h0.y) + bf2f(e0.y), 0.f) + fmaxf(bf2f(h1.y) + bf2f(e1.y), 0.f)
        + fmaxf(bf2f(h2.y) + bf2f(e2.y), 0.f) + fmaxf(bf2f(h3.y) + bf2f(e3.y), 0.f);
    a2 += fmaxf(bf2f(h0.z) + bf2f(e0.z), 0.f) + fmaxf(bf2f(h1.z) + bf2f(e1.z), 0.f)
        + fmaxf(bf2f(h2.z) + bf2f(e2.z), 0.f) + fmaxf(bf2f(h3.z) + bf2f(e3.z), 0.f);
    a3 += fmaxf(bf2f(h0.w) + bf2f(e0.w), 0.f) + fmaxf(bf2f(h1.w) + bf2f(e1.w), 0.f)
        + fmaxf(bf2f(h2.w) + bf2f(e2.w), 0.f) + fmaxf(bf2f(h3.w) + bf2f(e3.w), 0.f);
  }
  for (; i < end; ++i) {
    int2 se = csr[i];
    ushort4 ev = *(const ushort4*)(ea + (size_t)se.y * 256 + c);
    ushort4 hv = *(const ushort4*)(xb + (size_t)se.x * 256 + c);
    a0 += fmaxf(bf2f(hv.x) + bf2f(ev.x), 0.f);
    a1 += fmaxf(bf2f(hv.y) + bf2f(ev.y), 0.f);
    a2 += fmaxf(bf2f(hv.z) + bf2f(ev.z), 0.f);
    a3 += fmaxf(bf2f(hv.w) + bf2f(ev.w), 0.f);
  }
  u32x2 pk = {cvtpk(a0, a1), cvtpk(a2, a3)};
  *(u32x2*)(agg + (size_t)v * 256 + c) = pk;
}

// ---------------------------------------------------------------------------
// Fused pool+heads (r14): per graph, mean-pool h2 rows into LDS, then the
// head MLP -- removes the pooled global roundtrip and one dispatch.
// Block = 256 threads.
// ---------------------------------------------------------------------------
__global__ __launch_bounds__(256) void pool_head(
    const unsigned short* __restrict__ h2, const int* __restrict__ batch,
    const float* __restrict__ l1w, const float* __restrict__ l1b,
    const float* __restrict__ l2w, const float* __restrict__ l2b,
    const float* __restrict__ hSw, const float* __restrict__ hSb,
    const float* __restrict__ hPw, const float* __restrict__ hPb,
    const float* __restrict__ hNw, const float* __restrict__ hNb,
    float* __restrict__ out) {
  int g = blockIdx.x;
  int tid = threadIdx.x;
  int lane = tid & 63;   // col group (4 cols)
  int sub = tid >> 6;    // row offset 0..3
  __shared__ float p[256];
  __shared__ float g1[128];
  __shared__ float g2[64];
  __shared__ float4 red[4][64];

  int lo = 0, hi = N_NODES;
  while (lo < hi) { int mid = (lo + hi) >> 1; if (batch[mid] < g) lo = mid + 1; else hi = mid; }
  int start = lo;
  hi = N_NODES;
  while (lo < hi) { int mid = (lo + hi) >> 1; if (batch[mid] < g + 1) lo = mid + 1; else hi = mid; }
  int end = lo;
  float s0 = 0.f, s1 = 0.f, s2 = 0.f, s3 = 0.f;
  for (int r = start + sub; r < end; r += 4) {
    ushort4 hv = *(const ushort4*)(h2 + (size_t)r * 256 + lane * 4);
    s0 += bf2f(hv.x); s1 += bf2f(hv.y); s2 += bf2f(hv.z); s3 += bf2f(hv.w);
  }
  red[sub][lane] = make_float4(s0, s1, s2, s3);
  __syncthreads();
  if (sub == 0) {
    float4 a = red[0][lane], b = red[1][lane], cc = red[2][lane], d = red[3][lane];
    float inv = 1.0f / fmaxf((float)(end - start), 1.0f);
    p[lane * 4 + 0] = (a.x + b.x + cc.x + d.x) * inv;
    p[lane * 4 + 1] = (a.y + b.y + cc.y + d.y) * inv;
    p[lane * 4 + 2] = (a.z + b.z + cc.z + d.z) * inv;
    p[lane * 4 + 3] = (a.w + b.w + cc.w + d.w) * inv;
  }
  __syncthreads();

  if (tid < 128) {
    float a = l1b[tid];
#pragma unroll 8
    for (int k = 0; k < 256; ++k) a += p[k] * l1w[k * 128 + tid];
    g1[tid] = fmaxf(a, 0.f);
  }
  __syncthreads();
  if (tid < 64) {
    float b = l2b[tid];
#pragma unroll 8
    for (int k = 0; k < 128; ++k) b += g1[k] * l2w[k * 64 + tid];
    g2[tid] = fmaxf(b, 0.f);
  }
  __syncthreads();
  if (tid < 64) {
    float v = g2[tid];
    float s = v * hSw[tid], pq = v * hPw[tid], nq = v * hNw[tid];
#pragma unroll
    for (int off = 32; off > 0; off >>= 1) {
      s  += __shfl_down(s, off);
      pq += __shfl_down(pq, off);
      nq += __shfl_down(nq, off);
    }
    if (tid == 0) {
      out[g]                = s  + hSb[0];
      out[N_GRAPHS + g]     = pq + hPb[0];
      out[2 * N_GRAPHS + g] = nq + hNb[0];
    }
  }
}

// ---------------------------------------------------------------------------
extern "C" void kernel_launch(void* const* d_in, const int* in_sizes, int n_in,
                              void* d_out, int out_size, void* d_ws, size_t ws_size,
                              hipStream_t stream) {
  const float* x         = (const float*)d_in[0];
  const float* edge_attr = (const float*)d_in[1];
  const int*   ei        = (const int*)d_in[2];
  const int*   batch     = (const int*)d_in[3];
  const float* em_w1 = (const float*)d_in[4];  const float* em_b1 = (const float*)d_in[5];
  const float* em_w2 = (const float*)d_in[6];  const float* em_b2 = (const float*)d_in[7];
  const float* c1_w1 = (const float*)d_in[8];  const float* c1_b1 = (const float*)d_in[9];
  const float* c1_w2 = (const float*)d_in[10]; const float* c1_b2 = (const float*)d_in[11];
  const float* c2_w1 = (const float*)d_in[12]; const float* c2_b1 = (const float*)d_in[13];
  const float* c2_w2 = (const float*)d_in[14]; const float* c2_b2 = (const float*)d_in[15];
  const float* l1_w = (const float*)d_in[16];  const float* l1_b = (const float*)d_in[17];
  const float* l2_w = (const float*)d_in[18];  const float* l2_b = (const float*)d_in[19];
  const float* hS_w = (const float*)d_in[20];  const float* hS_b = (const float*)d_in[21];
  const float* hP_w = (const float*)d_in[22];  const float* hP_b = (const float*)d_in[23];
  const float* hN_w = (const float*)d_in[24];  const float* hN_b = (const float*)d_in[25];

  char* ws = (char*)d_ws;
  // layout (bytes):
  //   ea   @ 0           : E*256*2 = 409,600,000  (bf16, edge order; h2 later)
  //   agg  @ 409,600,000 : N*256*2 = 102,400,000  (bf16, MLP-ready: + self)
  //   xb   @ 512,000,000 : N*256*2 = 102,400,000  (bf16 copy of x)
  //   h1   @ 614,400,000 : N*256*2 = 102,400,000
  //   csr  @ 716,800,000 : 6,400,000; rp/bsum after
  //   wts  @ 724,992,000 : ~688,128 (fragment-ordered, contiguous block)
  unsigned short* ea     = (unsigned short*)ws;
  unsigned short* agg    = (unsigned short*)(ws + 409600000);
  unsigned short* xb     = (unsigned short*)(ws + 512000000);
  unsigned short* h1     = (unsigned short*)(ws + 614400000);
  unsigned short* h2     = ea;  // alias: ea dead after 2nd gather
  int2*           csr    = (int2*)(ws + 716800000);            // 6,400,000 B
  int*            rp     = (int*)(ws + 723200000);             //   800,000 B
  int*            bsum   = (int*)(ws + 724000000);             //     1,024 B
  unsigned short* wt     = (unsigned short*)(ws + 724992000);
  unsigned short* em_w1f = wt;                 // 16384 elems @ 0
  unsigned short* em_w2f = em_w1f + 16384;     // then 5 x 65536 contiguous
  unsigned short* c1_w1f = em_w2f + 65536;
  unsigned short* c1_w2f = c1_w1f + 65536;
  unsigned short* c2_w1f = c1_w2f + 65536;
  unsigned short* c2_w2f = c2_w1f + 65536;

  const int* srcI = ei;
  const int* dstI = ei + N_EDGES;

  // all 6 weight matrices -> fragment order, ONE launch (r14)
  wtrans_all<<<(344064 + 255) / 256, 256, 0, stream>>>(
      em_w1, em_w2, c1_w1, c1_w2, c2_w1, c2_w2, wt);

  // bf16 table: x (node features) -- edge_attr staged fp32-direct (r13)
  f2bf_bulk<<<(N_NODES * 256 / 8 + 255) / 256, 256, 0, stream>>>(x, xb, N_NODES * 256 / 8);

  // CSR build (by dst)
  hipMemsetAsync(rp, 0, (size_t)N_NODES * 4, stream);
  hist_deg<<<(N_EDGES + 255) / 256, 256, 0, stream>>>(dstI, rp);
  scan_block<<<(N_NODES + 2047) / 2048, 256, 0, stream>>>(rp, bsum);
  scan_bsum<<<1, 256, 0, stream>>>(bsum, (N_NODES + 2047) / 2048);
  scan_add<<<(N_NODES + 255) / 256, 256, 0, stream>>>(rp, bsum);
  csr_fill<<<N_EDGES / 256, 256, 0, stream>>>(srcI, dstI, rp, csr);

  // ea = edge MLP directly from fp32 edge_attr (no output relu)
  fused_mlp2<64, 0><<<N_EDGES / 64, 256, 0, stream>>>(
      edge_attr, nullptr, em_w1f, em_b1, em_w2f, em_b2, ea, 0);

  // conv1: gather (with self-term) -> pure-copy-staged MLP
  gather_agg<<<(N_NODES + 3) / 4, 256, 0, stream>>>(ea, xb, rp, csr, agg);
  fused_mlp2<256, 3><<<N_NODES / 64, 256, 0, stream>>>(
      nullptr, agg, c1_w1f, c1_b1, c1_w2f, c1_b2, h1, 1);

  // conv2
  gather_agg<<<(N_NODES + 3) / 4, 256, 0, stream>>>(ea, h1, rp, csr, agg);
  fused_mlp2<256, 3><<<N_NODES / 64, 256, 0, stream>>>(
      nullptr, agg, c2_w1f, c2_b1, c2_w2f, c2_b2, h2, 1);

  // fused pool + heads
  pool_head<<<N_GRAPHS, 256, 0, stream>>>(h2, batch, l1_w, l1_b, l2_w, l2_b,
                                          hS_w, hS_b, hP_w, hP_b, hN_w, hN_b,
                                          (float*)d_out);
}